// Round 2
// baseline (164.574 us; speedup 1.0000x reference)
//
#include <hip/hip_runtime.h>
#include <math.h>

#define C 100
#define WAVES 4
#define ROWS_PER_PASS 32                          // per block per pass
#define PASSES 4
#define ROWS_PER_BLOCK (ROWS_PER_PASS * PASSES)   // 128
#define PASS_FLOATS (ROWS_PER_PASS * C)           // 3200 floats = 12800 B
#define FULL_CHUNKS 12                            // 12 x 1024 B + 1 x 512 B
#define INV_NORM 0.3989422804014327f              // 1/sqrt(2*pi), STD = 1
#define WFAR     0.67102943f                      // exp(-inv_norm) = lim w(d)

// quad (4-lane) sum via DPP quad_perm — VALU only, no DS pipe
__device__ __forceinline__ float quad_sum(float x) {
    x += __int_as_float(__builtin_amdgcn_update_dpp(
            0, __float_as_int(x), 0xB1, 0xF, 0xF, true));  // [1,0,3,2]
    x += __int_as_float(__builtin_amdgcn_update_dpp(
            0, __float_as_int(x), 0x4E, 0xF, 0xF, true));  // [2,3,0,1]
    return x;
}
// octet (8-lane) sum: quad_sum then xor-4 exchange
__device__ __forceinline__ float oct_sum(float x) {
    x = quad_sum(x);
    x += __shfl_xor(x, 4);
    return x;
}

// Math (verified in prior rounds): w(d) = exp(code(d)-inv_norm),
// code(d) = inv_norm*exp(-d^2/2); w'(d) = w(d)-wfar, zero for |d|>6.
//   csum = 100*wfar + sum_{valid d} w'(|d|)
//   dot  = wfar*rowsum + sum_{|d|<=6} w'(d) s_{mu+d}
//   dotc = sum_{valid d} w(|d|)*code(|d|)
//   kl_row = (dotc - dot)/csum - inv_norm - log(csum) + log(sum_j exp s_j)
//
// v3: occupancy fix. v2 profiled latency-bound (Occ 24%, VALU 13%, HBM 9%):
// 51.2 KB LDS capped us at 3 blocks/CU. Halve the pass to 32 rows ->
// 2 x 12.8 KB buffers = 25.6 KB -> 6 blocks/CU (24 waves). Consume moves
// from quad-per-row to octet-per-row (8 lanes/row, 12-13 elems/lane).
// Octet layout has ~5-way LDS bank aliasing on 1/4 of banks — accepted:
// DS pipe is separate and overlappable at this occupancy.
__global__ __launch_bounds__(256, 6) void kl_main(
    const float* __restrict__ scores,
    const int*   __restrict__ labels,
    float* __restrict__ out, int n, float inv_n)
{
    __shared__ float buf[2][PASS_FLOATS];   // 2 x 12800 B
    __shared__ float wpart[WAVES];

    const int tid  = threadIdx.x;
    const int wave = tid >> 6, lane = tid & 63;
    const int rw   = lane >> 3;            // row within wave (0..7)
    const int sub8 = lane & 7;             // lane within octet
    const int rowInPassBase = wave * 8 + rw;   // 0..31

    const int blockRow0 = blockIdx.x * ROWS_PER_BLOCK;
    const size_t totalBytes = (size_t)n * C * 4;

    // prefetch labels for all passes up-front (retire before DMA chunks)
    int mu[PASSES];
    #pragma unroll
    for (int p = 0; p < PASSES; ++p) {
        int row = blockRow0 + p * ROWS_PER_PASS + rowInPassBase;
        mu[p] = (row < n) ? labels[row] : 0;
    }

    float acc = 0.f;

    // stage pass p into buf[b]: wave w DMAs chunks {w, w+4, w+8}; wave0 also
    // DMAs the tail 512-B half-chunk (lanes 0-31). vmcnt/pass: wave0=4, else 3.
    auto stage = [&](int p, int b) {
        const size_t byteBase = (size_t)(blockRow0 + p * ROWS_PER_PASS) * (C * 4);
        #pragma unroll
        for (int k = 0; k < 3; ++k) {
            int c = wave + k * WAVES;
            size_t off = byteBase + (size_t)c * 1024;
            if (off + 1024 > totalBytes) off = totalBytes - 1024; // no-op: n%32==0
            const char* src = (const char*)scores + off + lane * 16;
            __builtin_amdgcn_global_load_lds(
                (const __attribute__((address_space(1))) void*)src,
                (__attribute__((address_space(3))) void*)&buf[b][c * 256],
                16, 0, 0);
        }
        if (wave == 0) {
            size_t off = byteBase + (size_t)FULL_CHUNKS * 1024;   // +12288
            if (off + 512 > totalBytes) off = totalBytes - 512;
            if (lane < 32) {
                const char* src = (const char*)scores + off + lane * 16;
                __builtin_amdgcn_global_load_lds(
                    (const __attribute__((address_space(1))) void*)src,
                    (__attribute__((address_space(3))) void*)&buf[b][FULL_CHUNKS * 256],
                    16, 0, 0);
            }
        }
    };

    auto consume = [&](int p, int b) {
        const float* sp = &buf[b][rowInPassBase * C];
        // octet split of the row: offs {0,13,26,39,52,64,76,88}, cnt 13/13/13/13/12/12/12/12
        const int off = sub8 * 13 - max(sub8 - 4, 0);
        const float* spl = sp + off;
        float se = 0.f, rs = 0.f;
        #pragma unroll
        for (int i = 0; i < 12; ++i) {
            float s = spl[i];
            se += __expf(s);
            rs += s;
        }
        if (sub8 < 4) {            // 13th element for the first four octet lanes
            float s = spl[12];
            se += __expf(s);
            rs += s;
        }
        se = oct_sum(se);
        rs = oct_sum(rs);

        // 13-term window around mu, redundantly on all 8 lanes (broadcasts)
        const float WP[7] = {0.32897057f, 0.18369895f, 0.03722540f,
            0.00298049f, 8.9804e-5f, 9.9763e-7f, 4.0768e-9f};
        const float WC[7] = {0.39894228f, 0.20681926f, 0.03823936f,
            0.00298711f, 8.9816e-5f, 9.9765e-7f, 4.0768e-9f};
        float dotw = 0.f, csum = 100.f * WFAR, dotc = 0.f;
        const int m = mu[p];
        #pragma unroll
        for (int d = -6; d <= 6; ++d) {
            int idx  = m + d;
            bool ok  = (unsigned)idx < (unsigned)C;
            float s  = sp[min(max(idx, 0), C - 1)];
            int a    = d < 0 ? -d : d;               // compile-time
            float wv = ok ? WP[a] : 0.f;
            dotw  = fmaf(wv, s, dotw);
            csum += wv;
            dotc += ok ? WC[a] : 0.f;
        }

        int myrow = blockRow0 + p * ROWS_PER_PASS + rowInPassBase;
        if (sub8 == 0 && myrow < n) {
            float dot = fmaf(WFAR, rs, dotw);
            acc += (dotc - dot) / csum - INV_NORM - __logf(csum) + __logf(se);
        }
    };

    // ---- pipeline: counted vmcnt, raw barriers (never drain to 0 mid-loop)
    // VM(3): wave's own previous-pass chunks (3, wave0: 4 w/ slight over-wait)
    // complete; next pass's stay in flight. Barrier makes them block-visible.
    #define VMBAR(N) do { asm volatile("s_waitcnt vmcnt(" #N ")" ::: "memory"); \
                          __builtin_amdgcn_s_barrier();                          \
                          asm volatile("" ::: "memory"); } while (0)
    #define BAR()    do { asm volatile("" ::: "memory");                         \
                          __builtin_amdgcn_s_barrier();                          \
                          asm volatile("" ::: "memory"); } while (0)

    stage(0, 0);
    stage(1, 1);

    VMBAR(3);          // pass 0 landed (pass 1 still in flight)
    consume(0, 0);
    BAR();             // all waves done reading buf0
    stage(2, 0);

    VMBAR(3);          // pass 1 landed (pass 2 in flight)
    consume(1, 1);
    BAR();             // all waves done reading buf1
    stage(3, 1);

    VMBAR(3);          // pass 2 landed (pass 3 in flight)
    consume(2, 0);

    VMBAR(0);          // drain: pass 3 landed
    consume(3, 1);

    #undef VMBAR
    #undef BAR

    // wave reduce (only sub8==0 lanes nonzero) + block combine, 1 atomic/block
    #pragma unroll
    for (int off = 32; off > 0; off >>= 1)
        acc += __shfl_xor(acc, off, 64);
    if (lane == 0) wpart[wave] = acc;
    __syncthreads();
    if (tid == 0)
        atomicAdd(out, (wpart[0] + wpart[1] + wpart[2] + wpart[3]) * inv_n);
}

extern "C" void kernel_launch(void* const* d_in, const int* in_sizes, int n_in,
                              void* d_out, int out_size, void* d_ws, size_t ws_size,
                              hipStream_t stream)
{
    const float* scores = (const float*)d_in[0];
    const int*   labels = (const int*)d_in[1];
    float*       out    = (float*)d_out;

    int n = in_sizes[0] / C;   // 262144

    // d_out is poisoned (0xAA) before every timed launch — zero it first.
    hipMemsetAsync(d_out, 0, sizeof(float) * (size_t)out_size, stream);

    int blocks = (n + ROWS_PER_BLOCK - 1) / ROWS_PER_BLOCK;   // 2048
    kl_main<<<blocks, 256, 0, stream>>>(scores, labels, out, n, 1.0f / (float)n);
}

// Round 4
// 163.776 us; speedup vs baseline: 1.0049x; 1.0049x over previous
//
#include <hip/hip_runtime.h>
#include <math.h>

#define C 100
#define WAVES 4
#define ROWS_PER_PASS 32                          // per block per pass
#define PASSES 8
#define ROWS_PER_BLOCK (ROWS_PER_PASS * PASSES)   // 256 -> 1024 blocks, no tail
#define PASS_FLOATS (ROWS_PER_PASS * C)           // 3200 floats = 12800 B
#define FULL_CHUNKS 12                            // 12 x 1024 B + 1 x 512 B
#define INV_NORM 0.3989422804014327f              // 1/sqrt(2*pi), STD = 1
#define WFAR     0.67102943f                      // exp(-inv_norm) = lim w(d)

// quad (4-lane) sum via DPP quad_perm — VALU only, no DS pipe
__device__ __forceinline__ float quad_sum(float x) {
    x += __int_as_float(__builtin_amdgcn_update_dpp(
            0, __float_as_int(x), 0xB1, 0xF, 0xF, true));  // [1,0,3,2]
    x += __int_as_float(__builtin_amdgcn_update_dpp(
            0, __float_as_int(x), 0x4E, 0xF, 0xF, true));  // [2,3,0,1]
    return x;
}
// octet (8-lane) sum: quad_sum then xor-4 exchange
__device__ __forceinline__ float oct_sum(float x) {
    x = quad_sum(x);
    x += __shfl_xor(x, 4);
    return x;
}

// Math (verified in prior rounds): w(d) = exp(code(d)-inv_norm),
// code(d) = inv_norm*exp(-d^2/2); w'(d) = w(d)-wfar, zero for |d|>6.
//   csum = 100*wfar + sum_{valid d} w'(|d|)
//   dot  = wfar*rowsum + sum_{|d|<=6} w'(d) s_{mu+d}
//   dotc = sum_{valid d} w(|d|)*code(|d|)
//   kl_row = (dotc - dot)/csum - inv_norm - log(csum) + log(sum_j exp s_j)
//
// v4 (resubmit — round 3 was an infra failure, no data): v3's occupancy
// (25.6 KB LDS -> 6 blocks/CU, 24 waves/CU) + tail fix. 8 passes/block ->
// 256 rows/block -> 1024 blocks: whole grid co-resident in ONE dispatch
// round (capacity 1536), no ragged 512-block tail like v3's 2048-block
// grid. Exact per-wave counted vmcnt (wave0 issues 4 DMA/pass incl. the
// 512-B tail chunk, waves1-3 issue 3) via wave-uniform branch.
__global__ __launch_bounds__(256, 6) void kl_main(
    const float* __restrict__ scores,
    const int*   __restrict__ labels,
    float* __restrict__ out, int n, float inv_n)
{
    __shared__ float buf[2][PASS_FLOATS];   // 2 x 12800 B
    __shared__ float wpart[WAVES];

    const int tid  = threadIdx.x;
    const int wave = tid >> 6, lane = tid & 63;
    const int rw   = lane >> 3;                // row within wave (0..7)
    const int sub8 = lane & 7;                 // lane within octet
    const int rowInPassBase = wave * 8 + rw;   // 0..31

    const int blockRow0 = blockIdx.x * ROWS_PER_BLOCK;

    // prefetch labels for all passes up-front (oldest in vmcnt queue; retired
    // by the first counted wait, well before any mu[p] use)
    int mu[PASSES];
    #pragma unroll
    for (int p = 0; p < PASSES; ++p) {
        int row = blockRow0 + p * ROWS_PER_PASS + rowInPassBase;
        mu[p] = (row < n) ? labels[row] : 0;
    }

    float acc = 0.f;

    // stage pass p into buf[b]: wave w DMAs chunks {w, w+4, w+8}; wave0 also
    // DMAs the tail 512-B half-chunk (lanes 0-31). Issues/pass: wave0=4, else 3.
    // Grid is exact (n = 1024*256): every chunk in-bounds, no clamping needed.
    auto stage = [&](int p, int b) {
        const size_t byteBase = (size_t)(blockRow0 + p * ROWS_PER_PASS) * (C * 4);
        #pragma unroll
        for (int k = 0; k < 3; ++k) {
            int c = wave + k * WAVES;
            const char* src = (const char*)scores + byteBase + (size_t)c * 1024
                              + lane * 16;
            __builtin_amdgcn_global_load_lds(
                (const __attribute__((address_space(1))) void*)src,
                (__attribute__((address_space(3))) void*)&buf[b][c * 256],
                16, 0, 0);
        }
        if (wave == 0 && lane < 32) {
            const char* src = (const char*)scores + byteBase
                              + (size_t)FULL_CHUNKS * 1024 + lane * 16;
            __builtin_amdgcn_global_load_lds(
                (const __attribute__((address_space(1))) void*)src,
                (__attribute__((address_space(3))) void*)&buf[b][FULL_CHUNKS * 256],
                16, 0, 0);
        }
    };

    auto consume = [&](int p, int b) {
        const float* sp = &buf[b][rowInPassBase * C];
        // octet split of the row: offs {0,13,26,39,52,64,76,88}, cnt 13x4, 12x4
        const int off = sub8 * 13 - max(sub8 - 4, 0);
        const float* spl = sp + off;
        float se = 0.f, rs = 0.f;
        #pragma unroll
        for (int i = 0; i < 12; ++i) {
            float s = spl[i];
            se += __expf(s);
            rs += s;
        }
        if (sub8 < 4) {            // 13th element for the first four octet lanes
            float s = spl[12];
            se += __expf(s);
            rs += s;
        }
        se = oct_sum(se);
        rs = oct_sum(rs);

        // 13-term window around mu, redundantly on all 8 lanes (broadcasts)
        const float WP[7] = {0.32897057f, 0.18369895f, 0.03722540f,
            0.00298049f, 8.9804e-5f, 9.9763e-7f, 4.0768e-9f};
        const float WC[7] = {0.39894228f, 0.20681926f, 0.03823936f,
            0.00298711f, 8.9816e-5f, 9.9765e-7f, 4.0768e-9f};
        float dotw = 0.f, csum = 100.f * WFAR, dotc = 0.f;
        const int m = mu[p];
        #pragma unroll
        for (int d = -6; d <= 6; ++d) {
            int idx  = m + d;
            bool ok  = (unsigned)idx < (unsigned)C;
            float s  = sp[min(max(idx, 0), C - 1)];
            int a    = d < 0 ? -d : d;               // compile-time
            float wv = ok ? WP[a] : 0.f;
            dotw  = fmaf(wv, s, dotw);
            csum += wv;
            dotc += ok ? WC[a] : 0.f;
        }

        int myrow = blockRow0 + p * ROWS_PER_PASS + rowInPassBase;
        if (sub8 == 0 && myrow < n) {
            float dot = fmaf(WFAR, rs, dotw);
            acc += (dotc - dot) / csum - INV_NORM - __logf(csum) + __logf(se);
        }
    };

    // ---- pipeline: counted vmcnt (exact per wave), raw barriers; never
    // drain to 0 mid-loop. Each wave waits only for ITS OWN pass-p chunks,
    // then the barrier makes the whole pass block-visible.
    stage(0, 0);
    stage(1, 1);

    #pragma unroll
    for (int p = 0; p < PASSES; ++p) {
        if (p < PASSES - 1) {
            if (wave == 0) asm volatile("s_waitcnt vmcnt(4)" ::: "memory");
            else           asm volatile("s_waitcnt vmcnt(3)" ::: "memory");
        } else {
            asm volatile("s_waitcnt vmcnt(0)" ::: "memory");
        }
        __builtin_amdgcn_s_barrier();
        asm volatile("" ::: "memory");

        consume(p, p & 1);

        if (p < PASSES - 2) {
            asm volatile("" ::: "memory");
            __builtin_amdgcn_s_barrier();   // all waves done reading buf[p&1]
            asm volatile("" ::: "memory");
            stage(p + 2, p & 1);
        }
    }

    // wave reduce (only sub8==0 lanes nonzero) + block combine, 1 atomic/block
    #pragma unroll
    for (int off = 32; off > 0; off >>= 1)
        acc += __shfl_xor(acc, off, 64);
    if (lane == 0) wpart[wave] = acc;
    __syncthreads();
    if (tid == 0)
        atomicAdd(out, (wpart[0] + wpart[1] + wpart[2] + wpart[3]) * inv_n);
}

extern "C" void kernel_launch(void* const* d_in, const int* in_sizes, int n_in,
                              void* d_out, int out_size, void* d_ws, size_t ws_size,
                              hipStream_t stream)
{
    const float* scores = (const float*)d_in[0];
    const int*   labels = (const int*)d_in[1];
    float*       out    = (float*)d_out;

    int n = in_sizes[0] / C;   // 262144

    // d_out is poisoned (0xAA) before every timed launch — zero it first.
    hipMemsetAsync(d_out, 0, sizeof(float) * (size_t)out_size, stream);

    int blocks = (n + ROWS_PER_BLOCK - 1) / ROWS_PER_BLOCK;   // 1024
    kl_main<<<blocks, 256, 0, stream>>>(scores, labels, out, n, 1.0f / (float)n);
}

// Round 5
// 153.868 us; speedup vs baseline: 1.0696x; 1.0644x over previous
//
#include <hip/hip_runtime.h>
#include <math.h>

#define C 100
#define RPP 16                         // rows per pass per wave
#define WAVES 4                        // waves per 256-thread block
#define PASSES 4                       // passes per wave (register dbuf'd)
#define ROWS_PER_WAVE  (RPP * PASSES)           // 64
#define ROWS_PER_BLOCK (WAVES * ROWS_PER_WAVE)  // 256
#define NF4P (RPP * C / 4)             // 400 float4 per pass
#define INV_NORM 0.3989422804014327f   // 1/sqrt(2*pi), STD = 1
#define WFAR     0.67102943f           // exp(-inv_norm) = lim w(d)

// quad (4-lane) sum via DPP quad_perm — VALU only, no DS pipe
__device__ __forceinline__ float quad_sum(float x) {
    x += __int_as_float(__builtin_amdgcn_update_dpp(
            0, __float_as_int(x), 0xB1, 0xF, 0xF, true));  // [1,0,3,2]
    x += __int_as_float(__builtin_amdgcn_update_dpp(
            0, __float_as_int(x), 0x4E, 0xF, 0xF, true));  // [2,3,0,1]
    return x;
}

// Math (verified rounds 4/5 of prior session): w(d) = exp(code(d)-inv_norm),
// code(d) = inv_norm*exp(-d^2/2); w'(d) = w(d)-wfar, zero for |d|>6.
//   csum = 100*wfar + sum_{valid d} w'(|d|)
//   dot  = wfar*rowsum + sum_{|d|<=6} w'(d) s_{mu+d}
//   dotc = sum_{valid d} w(|d|)*code(|d|)
//   kl_row = (dotc - dot)/csum - inv_norm - log(csum) + log(sum_j exp s_j)
// (scores ~ N(0,1): exp(s) safe in fp32 without max-subtraction)
//
// v5 = exact revert to v0, the best harness-verified kernel (155.9/157.5 us).
// Rounds 1-4 established: (a) in-profile kernel time can be pushed well
// below the harness's 2x61us poison fills via global_load_lds + 6 blk/CU,
// but (b) the TIMED composite regresses ~6us for those BW-aggressive
// variants — the timed metric rewards the gentlest kernel (least HBM
// interference with the surrounding 86%-of-peak harness traffic), which is
// this register-pipelined version. Pipeline: per wave, register dbuf va/vb;
// loads for pass p+1 issued BEFORE pass p is consumed. Wave-private LDS
// slice, no __syncthreads in the hot path (per-wave DS ops are in-order ->
// single buffer safe). launch_bounds(256,4): whole grid co-resident.
__global__ __launch_bounds__(256, 4) void kl_main(
    const float* __restrict__ scores,
    const int*   __restrict__ labels,
    float* __restrict__ out, int n, float inv_n)
{
    __shared__ float sl[WAVES][RPP * C];   // 4 x 6400 B, wave-private
    __shared__ float wpart[WAVES];

    const int tid  = threadIdx.x;
    const int wave = tid >> 6, lane = tid & 63;
    const int r    = lane >> 2, sub  = lane & 3;   // quad r owns row r
    float* const mys = sl[wave];

    const int waveRow0 = blockIdx.x * ROWS_PER_BLOCK + wave * ROWS_PER_WAVE;

    float4 va[7], vb[7];
    int mua = 0, mub = 0;
    float acc = 0.f;

    auto issue = [&](float4* v, int p, int& mu) {
        const int rowBase = waveRow0 + p * RPP;
        const int nf4 = min(RPP, max(0, n - rowBase)) * (C / 4);
        const float4* g = (const float4*)(scores + (size_t)rowBase * C);
        #pragma unroll
        for (int c = 0; c < 7; ++c) {
            int i = lane + 64 * c;
            v[c] = (i < nf4) ? g[i] : make_float4(0.f, 0.f, 0.f, 0.f);
        }
        int myrow = rowBase + r;
        mu = (myrow < n) ? labels[myrow] : 0;
    };

    auto consume = [&](const float4* v, int p, int mu) {
        // stage to wave-private LDS; compiler waits only on v's loads
        float4* st = (float4*)mys;
        #pragma unroll
        for (int c = 0; c < 7; ++c) {
            int i = lane + 64 * c;
            if (i < NF4P) st[i] = v[c];
        }
        const float* sp  = &mys[r * C];
        const float* spl = sp + sub * 25;   // 2 lanes/bank: free
        float se = 0.f, rs = 0.f;
        #pragma unroll
        for (int i = 0; i < 25; ++i) {
            float s = spl[i];
            se += __expf(s);
            rs += s;
        }
        se = quad_sum(se);
        rs = quad_sum(rs);

        // 13-term window around mu, redundantly on all 4 lanes (broadcasts)
        const float WP[7] = {0.32897057f, 0.18369895f, 0.03722540f,
            0.00298049f, 8.9804e-5f, 9.9763e-7f, 4.0768e-9f};
        const float WC[7] = {0.39894228f, 0.20681926f, 0.03823936f,
            0.00298711f, 8.9816e-5f, 9.9765e-7f, 4.0768e-9f};
        float dotw = 0.f, csum = 100.f * WFAR, dotc = 0.f;
        #pragma unroll
        for (int d = -6; d <= 6; ++d) {
            int idx  = mu + d;
            bool ok  = (unsigned)idx < (unsigned)C;
            float s  = sp[min(max(idx, 0), C - 1)];
            int a    = d < 0 ? -d : d;               // compile-time
            float wv = ok ? WP[a] : 0.f;
            dotw  = fmaf(wv, s, dotw);
            csum += wv;
            dotc += ok ? WC[a] : 0.f;
        }

        int myrow = waveRow0 + p * RPP + r;
        if (sub == 0 && myrow < n) {
            float dot = fmaf(WFAR, rs, dotw);
            acc += (dotc - dot) / csum - INV_NORM - __logf(csum) + __logf(se);
        }
    };

    // software pipeline: always one pass of loads ahead
    issue(va, 0, mua);
    issue(vb, 1, mub);
    consume(va, 0, mua);
    issue(va, 2, mua);
    consume(vb, 1, mub);
    issue(vb, 3, mub);
    consume(va, 2, mua);
    consume(vb, 3, mub);

    // wave reduce (only sub==0 lanes nonzero) + block combine, 1 atomic/block
    #pragma unroll
    for (int off = 32; off > 0; off >>= 1)
        acc += __shfl_xor(acc, off, 64);
    if (lane == 0) wpart[wave] = acc;
    __syncthreads();
    if (tid == 0)
        atomicAdd(out, (wpart[0] + wpart[1] + wpart[2] + wpart[3]) * inv_n);
}

extern "C" void kernel_launch(void* const* d_in, const int* in_sizes, int n_in,
                              void* d_out, int out_size, void* d_ws, size_t ws_size,
                              hipStream_t stream)
{
    const float* scores = (const float*)d_in[0];
    const int*   labels = (const int*)d_in[1];
    float*       out    = (float*)d_out;

    int n = in_sizes[0] / C;   // 262144

    // d_out is poisoned (0xAA) before every timed launch — zero it first.
    hipMemsetAsync(d_out, 0, sizeof(float) * (size_t)out_size, stream);

    int blocks = (n + ROWS_PER_BLOCK - 1) / ROWS_PER_BLOCK;   // 1024
    kl_main<<<blocks, 256, 0, stream>>>(scores, labels, out, n, 1.0f / (float)n);
}